// Round 1
// baseline (318.769 us; speedup 1.0000x reference)
//
#include <hip/hip_runtime.h>

#define N 8192
#define LOGN 13
#define IN_DIM 128
#define HID 64
#define NC 2
#define MLPW 64

// ---------------- kernel 1: edge dedup + per-edge MLP + scatter ----------------
__global__ void edge_kernel(const float* __restrict__ adj,
                            const float* __restrict__ xdeg,
                            const float* __restrict__ ydeg,
                            const float* __restrict__ Wm1,
                            const float* __restrict__ bm1,
                            const float* __restrict__ Wm2,
                            const float* __restrict__ bm2,
                            const int* __restrict__ idx, int E,
                            unsigned int* __restrict__ bitmask,
                            int* __restrict__ uniq_cnt,
                            int* __restrict__ uniq_idx,
                            int* __restrict__ row_cnt,
                            int* __restrict__ col_cnt,
                            float* __restrict__ adj_mask)
{
    __shared__ float sWm1[3 * MLPW];
    __shared__ float sbm1[MLPW];
    __shared__ float sWm2[MLPW * 2];
    __shared__ float sbm2[2];
    for (int t = threadIdx.x; t < 3 * MLPW; t += blockDim.x) sWm1[t] = Wm1[t];
    for (int t = threadIdx.x; t < MLPW; t += blockDim.x) sbm1[t] = bm1[t];
    for (int t = threadIdx.x; t < MLPW * 2; t += blockDim.x) sWm2[t] = Wm2[t];
    if (threadIdx.x < 2) sbm2[threadIdx.x] = bm2[threadIdx.x];
    __syncthreads();

    int e = blockIdx.x * blockDim.x + threadIdx.x;
    if (e >= E) return;
    int g = idx[e];
    unsigned int word = ((unsigned int)g) >> 5;
    unsigned int bit = 1u << (g & 31);
    unsigned int old = atomicOr(&bitmask[word], bit);
    if (old & bit) return;                  // duplicate index: same p, skip

    // unique edge: record it
    int u = atomicAdd(uniq_cnt, 1);
    uniq_idx[u] = g;
    int r = g >> LOGN;
    int c = g & (N - 1);
    atomicAdd(&row_cnt[r], 1);
    atomicAdd(&col_cnt[c], 1);

    // per-edge MLP: feats=[adj,xdeg,ydeg] -> relu(W1)+b -> W2+b -> softmax[:,1]
    float f0 = adj[g];
    float f1 = xdeg[g];
    float f2 = ydeg[g];
    float l0 = sbm2[0], l1 = sbm2[1];
#pragma unroll 8
    for (int j = 0; j < MLPW; j++) {
        float h = f0 * sWm1[j] + f1 * sWm1[MLPW + j] + f2 * sWm1[2 * MLPW + j] + sbm1[j];
        h = fmaxf(h, 0.0f);
        l0 += h * sWm2[2 * j + 0];
        l1 += h * sWm2[2 * j + 1];
    }
    float p = 1.0f / (1.0f + expf(l0 - l1));
    adj_mask[(size_t)g] = p;
}

// ---------------- kernel 2: degree -> D^{-1/2} ----------------
__global__ void deg_kernel(const int* __restrict__ row_cnt, const int* __restrict__ col_cnt,
                           float* __restrict__ drow, float* __restrict__ dcol)
{
    int i = blockIdx.x * blockDim.x + threadIdx.x;
    if (i < N) {
        drow[i] = 1.0f / sqrtf((float)(row_cnt[i] + 1));   // +1 from identity
        dcol[i] = 1.0f / sqrtf((float)(col_cnt[i] + 1));
    }
}

// ---------------- kernel 3: exclusive prefix scan of row counts (one block) ----------------
__global__ void scan_kernel(const int* __restrict__ row_cnt, int* __restrict__ row_ptr)
{
    __shared__ int tot[1024];
    int t = threadIdx.x;
    int base = t * 8;
    int loc[8];
    int s = 0;
    for (int i = 0; i < 8; i++) { loc[i] = s; s += row_cnt[base + i]; }
    tot[t] = s;
    __syncthreads();
    for (int off = 1; off < 1024; off <<= 1) {
        int v = (t >= off) ? tot[t - off] : 0;
        __syncthreads();
        tot[t] += v;
        __syncthreads();
    }
    int excl = tot[t] - s;
    for (int i = 0; i < 8; i++) row_ptr[base + i] = excl + loc[i];
    if (t == 1023) row_ptr[N] = tot[1023];
}

// ---------------- kernel 4: scatter unique edges into CSR buckets ----------------
__global__ void fill_kernel(const int* __restrict__ uniq_cnt,
                            const int* __restrict__ uniq_idx,
                            const int* __restrict__ row_ptr,
                            int* __restrict__ row_fill,
                            int* __restrict__ csr_col)
{
    int u = blockIdx.x * blockDim.x + threadIdx.x;
    if (u >= *uniq_cnt) return;
    int g = uniq_idx[u];
    int r = g >> LOGN;
    int pos = atomicAdd(&row_fill[r], 1);
    csr_col[row_ptr[r] + pos] = g & (N - 1);
}

// ---------------- kernel 5: Y[j][d] = dcol[j] * (x[j,:] @ W1[:,d]) ----------------
__global__ __launch_bounds__(256) void xw1_kernel(const float* __restrict__ x,
                                                  const float* __restrict__ W1,
                                                  const float* __restrict__ dcol,
                                                  float* __restrict__ Y)
{
    __shared__ float sx[4][IN_DIM];
    int r0 = blockIdx.x * 4;
    for (int t = threadIdx.x; t < 4 * IN_DIM; t += 256)
        sx[t >> 7][t & 127] = x[(size_t)(r0 + (t >> 7)) * IN_DIM + (t & 127)];
    __syncthreads();
    int rr = threadIdx.x >> 6;
    int d = threadIdx.x & 63;
    float acc = 0.0f;
#pragma unroll 8
    for (int k = 0; k < IN_DIM; k++)
        acc += sx[rr][k] * W1[k * HID + d];
    int j = r0 + rr;
    Y[(size_t)j * HID + d] = dcol[j] * acc;
}

// ---------------- kernel 6: SpMM layer 1: hid = drow ⊙ (A @ Y + Y) ----------------
__global__ __launch_bounds__(256) void spmm1_kernel(const float* __restrict__ Y,
                                                    const int* __restrict__ row_ptr,
                                                    const int* __restrict__ csr_col,
                                                    const float* __restrict__ drow,
                                                    float* __restrict__ hid)
{
    int r = blockIdx.x * 4 + (threadIdx.x >> 6);
    int d = threadIdx.x & 63;
    int s = row_ptr[r], e = row_ptr[r + 1];
    float acc = Y[(size_t)r * HID + d];          // identity (+I) term
    int k = s;
    for (; k + 3 < e; k += 4) {
        int c0 = csr_col[k], c1 = csr_col[k + 1], c2 = csr_col[k + 2], c3 = csr_col[k + 3];
        acc += Y[(size_t)c0 * HID + d];
        acc += Y[(size_t)c1 * HID + d];
        acc += Y[(size_t)c2 * HID + d];
        acc += Y[(size_t)c3 * HID + d];
    }
    for (; k < e; k++) acc += Y[(size_t)csr_col[k] * HID + d];
    hid[(size_t)r * HID + d] = drow[r] * acc;
}

// ---------------- kernel 7: Zc[j] = dcol[j] * (hid[j,:] @ W2) ----------------
__global__ __launch_bounds__(256) void zc_kernel(const float* __restrict__ hid,
                                                 const float* __restrict__ W2,
                                                 const float* __restrict__ dcol,
                                                 float* __restrict__ Zc)
{
    int r = blockIdx.x * 4 + (threadIdx.x >> 6);
    int lane = threadIdx.x & 63;
    float h = hid[(size_t)r * HID + lane];
    float z0 = h * W2[lane * 2 + 0];
    float z1 = h * W2[lane * 2 + 1];
    for (int off = 32; off >= 1; off >>= 1) {
        z0 += __shfl_xor(z0, off, 64);
        z1 += __shfl_xor(z1, off, 64);
    }
    if (lane == 0) {
        Zc[r * 2 + 0] = dcol[r] * z0;
        Zc[r * 2 + 1] = dcol[r] * z1;
    }
}

// ---------------- kernel 8: SpMM layer 2: out = drow ⊙ (A @ Zc + Zc) ----------------
__global__ __launch_bounds__(256) void spmm2_kernel(const float* __restrict__ Zc,
                                                    const int* __restrict__ row_ptr,
                                                    const int* __restrict__ csr_col,
                                                    const float* __restrict__ drow,
                                                    float* __restrict__ out)
{
    int r = blockIdx.x * 4 + (threadIdx.x >> 6);
    int lane = threadIdx.x & 63;
    int s = row_ptr[r], e = row_ptr[r + 1];
    float a0 = 0.0f, a1 = 0.0f;
    for (int k = s + lane; k < e; k += 64) {
        int c = csr_col[k];
        a0 += Zc[c * 2 + 0];
        a1 += Zc[c * 2 + 1];
    }
    for (int off = 32; off >= 1; off >>= 1) {
        a0 += __shfl_xor(a0, off, 64);
        a1 += __shfl_xor(a1, off, 64);
    }
    if (lane == 0) {
        a0 += Zc[r * 2 + 0];                     // identity (+I) term
        a1 += Zc[r * 2 + 1];
        out[r * 2 + 0] = drow[r] * a0;
        out[r * 2 + 1] = drow[r] * a1;
    }
}

extern "C" void kernel_launch(void* const* d_in, const int* in_sizes, int n_in,
                              void* d_out, int out_size, void* d_ws, size_t ws_size,
                              hipStream_t stream)
{
    const float* x    = (const float*)d_in[0];
    const float* adj  = (const float*)d_in[1];
    const float* xdeg = (const float*)d_in[2];
    const float* ydeg = (const float*)d_in[3];
    const float* Wm1  = (const float*)d_in[4];
    const float* bm1  = (const float*)d_in[5];
    const float* Wm2  = (const float*)d_in[6];
    const float* bm2  = (const float*)d_in[7];
    const float* W1   = (const float*)d_in[8];
    const float* W2   = (const float*)d_in[9];
    const int*   idx  = (const int*)d_in[10];
    const int E = in_sizes[10];

    float* out = (float*)d_out;                       // [N*NC]
    float* adj_mask = out + (size_t)N * NC;           // [N*N]

    // ---- workspace carve (~18 MB) ----
    char* ws = (char*)d_ws;
    size_t off = 0;
    auto carve = [&](size_t bytes) -> void* {
        void* p = ws + off;
        off += (bytes + 255) & ~(size_t)255;
        return p;
    };
    unsigned int* bitmask = (unsigned int*)carve((size_t)N * N / 8);
    int* uniq_cnt = (int*)carve(sizeof(int));
    int* uniq_idx = (int*)carve((size_t)E * sizeof(int));
    int* row_cnt  = (int*)carve((size_t)N * sizeof(int));
    int* col_cnt  = (int*)carve((size_t)N * sizeof(int));
    int* row_ptr  = (int*)carve((size_t)(N + 1) * sizeof(int));
    int* row_fill = (int*)carve((size_t)N * sizeof(int));
    int* csr_col  = (int*)carve((size_t)E * sizeof(int));
    float* drow   = (float*)carve((size_t)N * sizeof(float));
    float* dcol   = (float*)carve((size_t)N * sizeof(float));
    float* Y      = (float*)carve((size_t)N * HID * sizeof(float));
    float* hid    = (float*)carve((size_t)N * HID * sizeof(float));
    float* Zc     = (float*)carve((size_t)N * NC * sizeof(float));

    hipMemsetAsync(bitmask, 0, (size_t)N * N / 8, stream);
    hipMemsetAsync(uniq_cnt, 0, sizeof(int), stream);
    hipMemsetAsync(row_cnt, 0, (size_t)N * sizeof(int), stream);
    hipMemsetAsync(col_cnt, 0, (size_t)N * sizeof(int), stream);
    hipMemsetAsync(row_fill, 0, (size_t)N * sizeof(int), stream);
    hipMemsetAsync(adj_mask, 0, (size_t)N * N * sizeof(float), stream);

    int eb = (E + 255) / 256;
    edge_kernel<<<eb, 256, 0, stream>>>(adj, xdeg, ydeg, Wm1, bm1, Wm2, bm2, idx, E,
                                        bitmask, uniq_cnt, uniq_idx, row_cnt, col_cnt, adj_mask);
    deg_kernel<<<(N + 255) / 256, 256, 0, stream>>>(row_cnt, col_cnt, drow, dcol);
    scan_kernel<<<1, 1024, 0, stream>>>(row_cnt, row_ptr);
    fill_kernel<<<eb, 256, 0, stream>>>(uniq_cnt, uniq_idx, row_ptr, row_fill, csr_col);
    xw1_kernel<<<N / 4, 256, 0, stream>>>(x, W1, dcol, Y);
    spmm1_kernel<<<N / 4, 256, 0, stream>>>(Y, row_ptr, csr_col, drow, hid);
    zc_kernel<<<N / 4, 256, 0, stream>>>(hid, W2, dcol, Zc);
    spmm2_kernel<<<N / 4, 256, 0, stream>>>(Zc, row_ptr, csr_col, drow, out);
}